// Round 23
// baseline (132.320 us; speedup 1.0000x reference)
//
#include <hip/hip_runtime.h>

typedef __bf16 bf16;
typedef __bf16 bf16x4 __attribute__((ext_vector_type(4)));
typedef __bf16 bf16x8 __attribute__((ext_vector_type(8)));
typedef float f32x4 __attribute__((ext_vector_type(4)));
typedef float f32x16 __attribute__((ext_vector_type(16)));
typedef unsigned u32x4 __attribute__((ext_vector_type(4)));

static constexpr int Bn = 2, Sn = 2048, Dn = 1024, Hn = 16, HDn = 64;

__device__ __forceinline__ void gload_lds16(const void* g, void* l) {
  __builtin_amdgcn_global_load_lds((__attribute__((address_space(1))) void*)g,
                                   (__attribute__((address_space(3))) void*)l, 16, 0, 0);
}

__device__ __forceinline__ f32x4 mfma_bf16_16x16x32(bf16x8 a, bf16x8 b, f32x4 c) {
  return __builtin_amdgcn_mfma_f32_16x16x32_bf16(a, b, c, 0, 0, 0);
}

__device__ __forceinline__ f32x16 mfma_bf16_32x32x16(bf16x8 a, bf16x8 b, f32x16 c) {
  return __builtin_amdgcn_mfma_f32_32x32x16_bf16(a, b, c, 0, 0, 0);
}

__device__ __forceinline__ float fast_exp2(float x) {
  float r;
  asm("v_exp_f32 %0, %1" : "=v"(r) : "v"(x));
  return r;
}

__device__ __forceinline__ unsigned cvt_pk_bf16(float lo, float hi) {
  unsigned r;
  asm("v_cvt_pk_bf16_f32 %0, %1, %2" : "=v"(r) : "v"(lo), "v"(hi));
  return r;
}

// Cross-half (lane ^ 32) combine via known-good shfl_xor (ds_bpermute path).
__device__ __forceinline__ float cross_half_max(float v) {
  return fmaxf(v, __shfl_xor(v, 32, 64));
}
__device__ __forceinline__ float cross_half_add(float v) {
  return v + __shfl_xor(v, 32, 64);
}
__device__ __forceinline__ unsigned shfl32u(unsigned u) {
  return (unsigned)__shfl_xor((int)u, 32, 64);
}

#define WAITCNT_VM(N) asm volatile("s_waitcnt vmcnt(" #N ")" ::: "memory")
#define WAITCNT_LGKM0 asm volatile("s_waitcnt lgkmcnt(0)" ::: "memory")

// ---------------- fp32 -> bf16 convert: weights only (4 segments) ----------------
struct CvtArgs {
  const float* in[4];
  bf16* out[4];
  int n4;
  float sc[4];
};

__global__ __launch_bounds__(256) void cvt_w4(CvtArgs a) {
  const float* in = a.in[blockIdx.z];
  bf16* out = a.out[blockIdx.z];
  const float s = a.sc[blockIdx.z];
  int i = blockIdx.x * 256 + threadIdx.x;
  const int stride = gridDim.x * 256;
  for (; i < a.n4; i += stride) {
    float4 v = reinterpret_cast<const float4*>(in)[i];
    bf16x4 o;
    o[0] = (bf16)(v.x * s); o[1] = (bf16)(v.y * s);
    o[2] = (bf16)(v.z * s); o[3] = (bf16)(v.w * s);
    reinterpret_cast<bf16x4*>(out)[i] = o;
  }
}

// ---------------- gemm_qkv: f32 A staged via global_load_lds, cvt at fragment read ------
// R20-proven core (108.8us). NEW (R23): z==2 (V) writes its C-tile TRANSPOSED directly
// to vt[(b*Dn+d)*Sn+s] via a 2-pass LDS round-trip in the dead staging buffer, removing
// the standalone transpose kernel (16MB traffic + launch). Direct transposed global
// write would be a 4KB-stride scatter; LDS pass keeps global stores coalesced (same
// 64B-chunk pattern the old transpose used). K-loop's final __syncthreads retires all
// staging reads before the transpose buffer overwrites the staging LDS (R10 lesson).
// 768 blocks = 8 XCD-chunks x 96; orig = x + 8y + 256z.
__global__ __launch_bounds__(256) void gemm_qkv(
    const float* __restrict__ qa, const bf16* __restrict__ wq, bf16* __restrict__ qo,
    const float* __restrict__ ka, const bf16* __restrict__ wk, bf16* __restrict__ ko,
    const float* __restrict__ va, const bf16* __restrict__ wv, bf16* __restrict__ vt) {
  const int n = blockIdx.x;
  const int orig = (n & 7) * 96 + (n >> 3);  // chunked XCD remap (bijective 8x96)
  const int x = orig & 7, y = (orig >> 3) & 31, z = orig >> 8;
  const float* A; const bf16* Bw;
  if (z == 0)      { A = qa; Bw = wq; }
  else if (z == 1) { A = ka; Bw = wk; }
  else             { A = va; Bw = wv; }

  const int t = threadIdx.x;
  const int l = t & 63, w = t >> 6;
  const int wr = w >> 1, wc = w & 1;
  const int lc = l & 15, lg = l >> 4;
  const int row0 = y * 128, col0 = x * 128;

  __shared__ char smem[24576];
  float* Asf = (float*)smem;          // 16KB: f32 A-tile, row = 128B = 8 chunks
  bf16* Bs = (bf16*)(smem + 16384);   // 8KB

  f32x4 acc[4][4] = {};

  for (int k0 = 0; k0 < Dn; k0 += 32) {
    // stage A (f32): 1024 chunks, 4/thread; slot j holds source chunk j^(r&7)
#pragma unroll
    for (int i = 0; i < 4; ++i) {
      const int c = i * 256 + t;
      const int r = c >> 3;
      const int sj = (c & 7) ^ (r & 7);
      gload_lds16(A + (size_t)(row0 + r) * Dn + k0 + sj * 4, smem + c * 16);
    }
    // stage B (bf16): 512 chunks, 2/thread (R13-proven layout)
#pragma unroll
    for (int i = 0; i < 2; ++i) {
      const int c = i * 256 + t;
      const int r = c >> 2;
      const int scc = (c & 3) ^ (r & 3);
      gload_lds16(Bw + (size_t)(col0 + r) * Dn + k0 + scc * 8, Bs + c * 8);
    }
    __syncthreads();

    bf16x8 af[4], bfr[4];
#pragma unroll
    for (int m = 0; m < 4; ++m) {
      const int r = wr * 64 + m * 16 + lc;
      const int sA = (2 * lg) ^ (r & 7);
      const int sB2 = (2 * lg + 1) ^ (r & 7);
      const float4 fa = *reinterpret_cast<const float4*>(Asf + r * 32 + sA * 4);
      const float4 fb = *reinterpret_cast<const float4*>(Asf + r * 32 + sB2 * 4);
      u32x4 u;
      u[0] = cvt_pk_bf16(fa.x, fa.y);
      u[1] = cvt_pk_bf16(fa.z, fa.w);
      u[2] = cvt_pk_bf16(fb.x, fb.y);
      u[3] = cvt_pk_bf16(fb.z, fb.w);
      af[m] = __builtin_bit_cast(bf16x8, u);
    }
#pragma unroll
    for (int nn = 0; nn < 4; ++nn) {
      const int r = wc * 64 + nn * 16 + lc;
      bfr[nn] = *reinterpret_cast<const bf16x8*>(Bs + r * 32 + ((lg ^ (r & 3)) * 8));
    }
#pragma unroll
    for (int m = 0; m < 4; ++m)
#pragma unroll
      for (int nn = 0; nn < 4; ++nn)
        acc[m][nn] = mfma_bf16_16x16x32(af[m], bfr[nn], acc[m][nn]);
    __syncthreads();  // final iteration: all staging LDS reads retired block-wide
  }

  if (z < 2) {
    bf16* C = (z == 0) ? qo : ko;
#pragma unroll
    for (int m = 0; m < 4; ++m) {
      const int rbase = row0 + wr * 64 + m * 16 + lg * 4;
#pragma unroll
      for (int nn = 0; nn < 4; ++nn) {
        const int col = col0 + wc * 64 + nn * 16 + lc;
#pragma unroll
        for (int j = 0; j < 4; ++j)
          C[(size_t)(rbase + j) * Dn + col] = (bf16)acc[m][nn][j];
      }
    }
  } else {
    // ---- transposed V write: 2 passes of 64 cols through tb[64][136] bf16 ----
    bf16* tb = (bf16*)smem;              // 17,408B < 24,576B (staging dead)
    const int bb = row0 >> 11;           // batch (128-row tile never spans b)
    const int sbase = row0 & 2047;
    const int dr = t >> 2;               // 0..63 (d-local row in pass)
    const int sq = (t & 3) * 32;         // s-quarter
#pragma unroll
    for (int p = 0; p < 2; ++p) {
      if (p) __syncthreads();            // pass-0 reads retired before pass-1 writes
      if (wc == p) {
        // this wave-pair owns cols p*64 + nn*16+lc; lane's 4 j-rows are contiguous
#pragma unroll
        for (int m = 0; m < 4; ++m) {
          const int rl = wr * 64 + m * 16 + lg * 4;  // row (s-local)
#pragma unroll
          for (int nn = 0; nn < 4; ++nn) {
            const int cl = nn * 16 + lc;             // col within pass
            bf16x4 o4;
#pragma unroll
            for (int j = 0; j < 4; ++j) o4[j] = (bf16)acc[m][nn][j];
            *reinterpret_cast<bf16x4*>(&tb[cl * 136 + rl]) = o4;  // b64, 8B-aligned
          }
        }
      }
      __syncthreads();
      // all 256 threads: stream 64 d-rows x 128 s to global (coalesced 16B/lane)
      const size_t dbase = ((size_t)bb * Dn + col0 + p * 64 + dr) * Sn + sbase + sq;
#pragma unroll
      for (int u = 0; u < 4; ++u) {
        const bf16x8 vv = *reinterpret_cast<const bf16x8*>(&tb[dr * 136 + sq + u * 8]);
        *reinterpret_cast<bf16x8*>(&vt[dbase + u * 8]) = vv;
      }
    }
  }
}

// ---------------- gemm_out: 128x128 tile, in-block K-split (8 waves; R19-proven) --------
__global__ __launch_bounds__(512) void gemm_out_f32(const bf16* __restrict__ A,
                                                    const bf16* __restrict__ Bw,
                                                    float* __restrict__ C) {
  const int n = blockIdx.x;
  const int orig = (n & 7) * 32 + (n >> 3);  // chunked XCD remap (bijective 8x32)
  const int x = orig & 7, y = orig >> 3;
  const int row0 = y * 128, col0 = x * 128;

  const int t = threadIdx.x;
  const int half = t >> 8;       // 0: K[0,512), 1: K[512,1024)
  const int tl = t & 255;
  const int l = tl & 63, wl = tl >> 6;
  const int wr = wl >> 1, wc = wl & 1;
  const int lc = l & 15, lg = l >> 4;

  __shared__ char smem[65536];   // staging: 2 x 16KB; merge: full 64KB f32 tile
  bf16* As = (bf16*)(smem + half * 16384);
  bf16* Bs = (bf16*)(smem + half * 16384 + 8192);

  f32x4 acc[4][4] = {};
  const int kbase = half * 512;

  for (int k0i = 0; k0i < 512; k0i += 32) {
    const int k0 = kbase + k0i;
#pragma unroll
    for (int i = 0; i < 2; ++i) {
      const int c = i * 256 + tl;
      const int r = c >> 2;
      const int scc = (c & 3) ^ (r & 3);
      gload_lds16(A + (size_t)(row0 + r) * Dn + k0 + scc * 8, As + c * 8);
      gload_lds16(Bw + (size_t)(col0 + r) * Dn + k0 + scc * 8, Bs + c * 8);
    }
    __syncthreads();

    bf16x8 af[4], bfr[4];
#pragma unroll
    for (int m = 0; m < 4; ++m) {
      const int r = wr * 64 + m * 16 + lc;
      af[m] = *reinterpret_cast<const bf16x8*>(As + r * 32 + ((lg ^ (r & 3)) * 8));
    }
#pragma unroll
    for (int nn = 0; nn < 4; ++nn) {
      const int r = wc * 64 + nn * 16 + lc;
      bfr[nn] = *reinterpret_cast<const bf16x8*>(Bs + r * 32 + ((lg ^ (r & 3)) * 8));
    }
#pragma unroll
    for (int m = 0; m < 4; ++m)
#pragma unroll
      for (int nn = 0; nn < 4; ++nn)
        acc[m][nn] = mfma_bf16_16x16x32(af[m], bfr[nn], acc[m][nn]);
    __syncthreads();  // last iteration: staging reads retired before publish
  }

  float* Op = (float*)smem;  // [128][128] f32
  if (half == 1) {
#pragma unroll
    for (int m = 0; m < 4; ++m) {
      const int rl = wr * 64 + m * 16 + lg * 4;
#pragma unroll
      for (int nn = 0; nn < 4; ++nn) {
        const int cl = wc * 64 + nn * 16 + lc;
#pragma unroll
        for (int j = 0; j < 4; ++j)
          Op[(rl + j) * 128 + cl] = acc[m][nn][j];
      }
    }
  }
  __syncthreads();

  if (half == 0) {
#pragma unroll
    for (int m = 0; m < 4; ++m) {
      const int rl = wr * 64 + m * 16 + lg * 4;
#pragma unroll
      for (int nn = 0; nn < 4; ++nn) {
        const int cl = wc * 64 + nn * 16 + lc;
#pragma unroll
        for (int j = 0; j < 4; ++j)
          C[(size_t)(row0 + rl + j) * Dn + col0 + cl] =
              acc[m][nn][j] + Op[(rl + j) * 128 + cl];
      }
    }
  }
}

// ---------------- causal flash attention (v11: KV-split + paired qt, uniform) ------------
// (R13-proven kernel, unchanged: ~50us, occupancy 18.6%)
__global__ __launch_bounds__(512) void flash_attn(const bf16* __restrict__ qp,
                                                  const bf16* __restrict__ kp,
                                                  const bf16* __restrict__ vt,
                                                  bf16* __restrict__ ctx) {
  const int n = blockIdx.x;
  const int g = (n & 7) + 8 * (n >> 6);
  const int pid = (n >> 3) & 7;
  const int h = g & 15;
  const int b = g >> 4;
  const int t = threadIdx.x, w = t >> 6, l = t & 63;
  const int lq = l & 31, hi = l >> 5;
  const int half = w >> 2;             // 0: chunk0 waves, 1: chunk1 waves

  __shared__ char smem[81920];
  char* my = smem + half * 40960;      // my half's staging region

  const int tl = t & 255;
  const int rl = tl >> 3;
  const int scc = (tl & 7) ^ (rl & 7);
  const bf16* kbase = kp + ((size_t)b * Sn + rl) * Dn + h * HDn + scc * 8;
  const bf16* vbase = vt + ((size_t)b * Dn + h * HDn + rl) * Sn + scc * 8;

  for (int ph = 0; ph < 2; ++ph) {
    const int qt = ph ? pid : 15 - pid;
    const int qrow0 = qt * 128 + (w & 3) * 32;
    const int cnt = qt + 1;            // tiles per chunk (same for both halves)
    const int tbase = half * cnt;

    auto STAGE = [&](int i) {
      const int kv0 = (tbase + i) * 64;
      char* Kd = my + (i & 1) * 8192 + tl * 16;
      char* Vd = my + 16384 + (i % 3) * 8192 + tl * 16;
      const bf16* ks = kbase + (size_t)kv0 * Dn;
      const bf16* vs = vbase + kv0;
#pragma unroll
      for (int ii = 0; ii < 2; ++ii) {
        gload_lds16(ks + (size_t)ii * 32 * Dn, Kd + ii * 4096);
        gload_lds16(vs + (size_t)ii * 32 * Sn, Vd + ii * 4096);
      }
    };

    bf16x8 qf[4];
#pragma unroll
    for (int kk = 0; kk < 4; ++kk)
      qf[kk] = *reinterpret_cast<const bf16x8*>(
          qp + ((size_t)b * Sn + qrow0 + lq) * Dn + h * HDn + kk * 16 + hi * 8);

    f32x16 oacc0 = {}, oacc1 = {};
    float mrow = -1e30f, lsum = 0.0f;

    auto QK = [&](int i, f32x16& s0_, f32x16& s1_) {
      const char* Kc = my + (i & 1) * 8192;
      __builtin_amdgcn_s_setprio(1);
#pragma unroll
      for (int kk = 0; kk < 4; ++kk) {
        const int ch = kk * 2 + hi;
        const int r0 = lq, r1 = 32 + lq;
        const bf16x8 k0 = *reinterpret_cast<const bf16x8*>(Kc + r0 * 128 + ((ch ^ (r0 & 7)) << 4));
        const bf16x8 k1 = *reinterpret_cast<const bf16x8*>(Kc + r1 * 128 + ((ch ^ (r1 & 7)) << 4));
        s0_ = mfma_bf16_32x32x16(k0, qf[kk], s0_);
        s1_ = mfma_bf16_32x32x16(k1, qf[kk], s1_);
      }
      __builtin_amdgcn_s_setprio(0);
    };

    auto SMPV = [&](int i, f32x16& s0, f32x16& s1) {
      const int kv0 = (tbase + i) * 64;
      const char* Vc = my + 16384 + (i % 3) * 8192;

      if (kv0 + 63 > qrow0) {
        const int qg = qrow0 + lq;
#pragma unroll
        for (int r = 0; r < 16; ++r) {
          const int kvl = (r & 3) + 8 * (r >> 2) + 4 * hi;
          if (kv0 + kvl > qg)      s0[r] = -1e30f;
          if (kv0 + 32 + kvl > qg) s1[r] = -1e30f;
        }
      }

      float mx[8];
#pragma unroll
      for (int i2 = 0; i2 < 8; ++i2)
        mx[i2] = fmaxf(fmaxf(s0[i2], s0[i2 + 8]), fmaxf(s1[i2], s1[i2 + 8]));
#pragma unroll
      for (int i2 = 0; i2 < 4; ++i2) mx[i2] = fmaxf(mx[i2], mx[i2 + 4]);
      const float tmax_own = fmaxf(fmaxf(mx[0], mx[1]), fmaxf(mx[2], mx[3]));
      const float tmax = cross_half_max(tmax_own);

      float alpha = 1.0f;
      if (!__all(tmax <= mrow + 8.0f)) {  // defer-max (T13)
        const float mn = fmaxf(mrow, tmax);
        alpha = fast_exp2(mrow - mn);
        mrow = mn;
#pragma unroll
        for (int r = 0; r < 16; ++r) { oacc0[r] *= alpha; oacc1[r] *= alpha; }
      }
#pragma unroll
      for (int r = 0; r < 16; ++r) {
        s0[r] = fast_exp2(s0[r] - mrow);
        s1[r] = fast_exp2(s1[r] - mrow);
      }
      float sm[8];
#pragma unroll
      for (int i2 = 0; i2 < 8; ++i2)
        sm[i2] = (s0[i2] + s0[i2 + 8]) + (s1[i2] + s1[i2 + 8]);
#pragma unroll
      for (int i2 = 0; i2 < 4; ++i2) sm[i2] += sm[i2 + 4];
      float rsum = (sm[0] + sm[1]) + (sm[2] + sm[3]);
      rsum = cross_half_add(rsum);
      lsum = lsum * alpha + rsum;

      u32x4 pw[4];
#pragma unroll
      for (int c2 = 0; c2 < 4; ++c2) {
        const f32x16& S = (c2 < 2) ? s0 : s1;
        const int base = (c2 & 1) * 8;
        const unsigned u0 = cvt_pk_bf16(S[base + 0], S[base + 1]);
        const unsigned u1 = cvt_pk_bf16(S[base + 2], S[base + 3]);
        const unsigned u2 = cvt_pk_bf16(S[base + 4], S[base + 5]);
        const unsigned u3 = cvt_pk_bf16(S[base + 6], S[base + 7]);
        const unsigned r1 = shfl32u(hi ? u0 : u2);
        const unsigned r2 = shfl32u(hi ? u1 : u3);
        pw[c2][0] = hi ? r1 : u0;
        pw[c2][1] = hi ? r2 : u1;
        pw[c2][2] = hi ? u2 : r1;
        pw[c2][3] = hi ? u3 : r2;
      }

      __builtin_amdgcn_s_setprio(1);
#pragma unroll
      for (int kk = 0; kk < 4; ++kk) {
        const bf16x8 pf = __builtin_bit_cast(bf16x8, pw[kk]);
        const int ch = kk * 2 + hi;
        const int r0 = lq, r1 = 32 + lq;
        const bf16x8 v0 = *reinterpret_cast<const bf16x8*>(Vc + r0 * 128 + ((ch ^ (r0 & 7)) << 4));
        const bf16x8 v1 = *reinterpret_cast<const bf16x8*>(Vc + r1 * 128 + ((ch ^ (r1 & 7)) << 4));
        oacc0 = mfma_bf16_32x32x16(v0, pf, oacc0);
        oacc1 = mfma_bf16_32x32x16(v1, pf, oacc1);
      }
      __builtin_amdgcn_s_setprio(0);
    };

    // phase-top barrier: prior-phase epilogue LDS reads retired before STAGE writes
    __builtin_amdgcn_s_barrier();
    __builtin_amdgcn_sched_barrier(0);

    STAGE(0);
    if (cnt > 1) { STAGE(1); WAITCNT_VM(4); } else { WAITCNT_VM(0); }
    __builtin_amdgcn_sched_barrier(0);
    __builtin_amdgcn_s_barrier();
    __builtin_amdgcn_sched_barrier(0);

    f32x16 sp0 = {}, sp1 = {};
    if (tbase * 64 <= qrow0 + 31) QK(0, sp0, sp1);

    for (int i = 0; i < cnt; ++i) {
      WAITCNT_VM(0);
      __builtin_amdgcn_sched_barrier(0);
      __builtin_amdgcn_s_barrier();
      __builtin_amdgcn_sched_barrier(0);

      if (i + 2 < cnt) STAGE(i + 2);
      f32x16 sn0 = {}, sn1 = {};
      if (i + 1 < cnt && (tbase + i + 1) * 64 <= qrow0 + 31) QK(i + 1, sn0, sn1);
      if ((tbase + i) * 64 <= qrow0 + 31) SMPV(i, sp0, sp1);
      sp0 = sn0; sp1 = sn1;
      WAITCNT_LGKM0;
    }

    // race-fix barrier (R10 lesson)
    __builtin_amdgcn_s_barrier();
    __builtin_amdgcn_sched_barrier(0);

    float* Op = (float*)smem;
    float* Ml = (float*)(smem + 33280);
    const int lrow = (w & 3) * 32 + lq;

    if (half == 1) {
#pragma unroll
      for (int r = 0; r < 16; ++r) {
        const int d = (r & 3) + 8 * (r >> 2) + 4 * hi;
        Op[lrow * 65 + d]      = oacc0[r];
        Op[lrow * 65 + 32 + d] = oacc1[r];
      }
      if (hi == 0) { Ml[lrow] = mrow; Ml[128 + lrow] = lsum; }
    }
    WAITCNT_LGKM0;
    __builtin_amdgcn_s_barrier();
    __builtin_amdgcn_sched_barrier(0);

    if (half == 0) {
      const float m1 = Ml[lrow], l1 = Ml[128 + lrow];
      const float mm = fmaxf(mrow, m1);
      const float a0 = fast_exp2(mrow - mm);
      const float a1 = fast_exp2(m1 - mm);
      const float inv = 1.0f / (lsum * a0 + l1 * a1);

      bf16* ep = (bf16*)(smem + 40960 + w * 4608);
#pragma unroll
      for (int dt = 0; dt < 2; ++dt) {
        const f32x16& O = dt ? oacc1 : oacc0;
#pragma unroll
        for (int g2 = 0; g2 < 4; ++g2) {
          bf16x4 o4;
#pragma unroll
          for (int jj = 0; jj < 4; ++jj) {
            const int d = dt * 32 + 8 * g2 + 4 * hi + jj;
            const float o1 = Op[lrow * 65 + d];
            o4[jj] = (bf16)((O[g2 * 4 + jj] * a0 + o1 * a1) * inv);
          }
          const int d0 = dt * 32 + g2 * 8 + hi * 4;
          *reinterpret_cast<bf16x4*>(&ep[lq * 72 + d0]) = o4;
        }
      }
      WAITCNT_LGKM0;
      __builtin_amdgcn_sched_barrier(0);
#pragma unroll
      for (int i = 0; i < 4; ++i) {
        const int q = i * 8 + (l >> 3);
        const int d0 = (l & 7) * 8;
        const bf16x8 vv = *reinterpret_cast<const bf16x8*>(&ep[q * 72 + d0]);
        *reinterpret_cast<bf16x8*>(
            &ctx[((size_t)b * Sn + qrow0 + q) * Dn + h * HDn + d0]) = vv;
      }
    }
  }
}

// ---------------- launch ----------------
extern "C" void kernel_launch(void* const* d_in, const int* in_sizes, int n_in,
                              void* d_out, int out_size, void* d_ws, size_t ws_size,
                              hipStream_t stream) {
  const float* q  = (const float*)d_in[0];
  const float* k  = (const float*)d_in[1];
  const float* v  = (const float*)d_in[2];
  // d_in[3] = causal mask (structure known; unused)
  const float* Wq = (const float*)d_in[4];
  const float* Wk = (const float*)d_in[5];
  const float* Wv = (const float*)d_in[6];
  const float* Wo = (const float*)d_in[7];

  constexpr size_t BSD = (size_t)Bn * Sn * Dn;
  constexpr size_t DD  = (size_t)Dn * Dn;

  char* p = (char*)d_ws;
  bf16* ctxb = (bf16*)p; p += BSD * 2;
  bf16* vtb  = (bf16*)p; p += BSD * 2;
  p += BSD * 2;
  bf16* qpb = (bf16*)p; p += BSD * 2;
  bf16* kpb = (bf16*)p; p += BSD * 2;
  p += BSD * 2;                        // (was vpb; now unused — V^T written directly)
  bf16* wqb = (bf16*)p; p += DD * 2;
  bf16* wkb = (bf16*)p; p += DD * 2;
  bf16* wvb = (bf16*)p; p += DD * 2;
  bf16* wob = (bf16*)p; p += DD * 2;

  // fold softmax scale (1/sqrt(64)=1/8) and log2(e) into Wq for exp2-domain softmax
  const float wq_scale = 0.125f * 1.4426950408889634f;

  CvtArgs ca;
  ca.in[0] = Wq; ca.out[0] = wqb; ca.sc[0] = wq_scale;
  ca.in[1] = Wk; ca.out[1] = wkb; ca.sc[1] = 1.0f;
  ca.in[2] = Wv; ca.out[2] = wvb; ca.sc[2] = 1.0f;
  ca.in[3] = Wo; ca.out[3] = wob; ca.sc[3] = 1.0f;
  ca.n4 = (int)(DD / 4);
  cvt_w4<<<dim3(256, 1, 4), 256, 0, stream>>>(ca);

  gemm_qkv<<<dim3(768), 256, 0, stream>>>(
      q, wqb, qpb, k, wkb, kpb, v, wvb, vtb);

  flash_attn<<<dim3(256), 512, 0, stream>>>(qpb, kpb, vtb, ctxb);

  gemm_out_f32<<<dim3(256), 512, 0, stream>>>(ctxb, wob, (float*)d_out);

  (void)in_sizes; (void)n_in; (void)out_size; (void)ws_size;
}

// Round 24
// 108.694 us; speedup vs baseline: 1.2174x; 1.2174x over previous
//
#include <hip/hip_runtime.h>

typedef __bf16 bf16;
typedef __bf16 bf16x4 __attribute__((ext_vector_type(4)));
typedef __bf16 bf16x8 __attribute__((ext_vector_type(8)));
typedef float f32x4 __attribute__((ext_vector_type(4)));
typedef float f32x16 __attribute__((ext_vector_type(16)));
typedef unsigned u32x4 __attribute__((ext_vector_type(4)));

static constexpr int Bn = 2, Sn = 2048, Dn = 1024, Hn = 16, HDn = 64;

__device__ __forceinline__ void gload_lds16(const void* g, void* l) {
  __builtin_amdgcn_global_load_lds((__attribute__((address_space(1))) void*)g,
                                   (__attribute__((address_space(3))) void*)l, 16, 0, 0);
}

__device__ __forceinline__ f32x4 mfma_bf16_16x16x32(bf16x8 a, bf16x8 b, f32x4 c) {
  return __builtin_amdgcn_mfma_f32_16x16x32_bf16(a, b, c, 0, 0, 0);
}

__device__ __forceinline__ f32x16 mfma_bf16_32x32x16(bf16x8 a, bf16x8 b, f32x16 c) {
  return __builtin_amdgcn_mfma_f32_32x32x16_bf16(a, b, c, 0, 0, 0);
}

__device__ __forceinline__ float fast_exp2(float x) {
  float r;
  asm("v_exp_f32 %0, %1" : "=v"(r) : "v"(x));
  return r;
}

__device__ __forceinline__ unsigned cvt_pk_bf16(float lo, float hi) {
  unsigned r;
  asm("v_cvt_pk_bf16_f32 %0, %1, %2" : "=v"(r) : "v"(lo), "v"(hi));
  return r;
}

// Cross-half (lane ^ 32) combine via known-good shfl_xor (ds_bpermute path).
__device__ __forceinline__ float cross_half_max(float v) {
  return fmaxf(v, __shfl_xor(v, 32, 64));
}
__device__ __forceinline__ float cross_half_add(float v) {
  return v + __shfl_xor(v, 32, 64);
}
__device__ __forceinline__ unsigned shfl32u(unsigned u) {
  return (unsigned)__shfl_xor((int)u, 32, 64);
}

#define WAITCNT_VM(N) asm volatile("s_waitcnt vmcnt(" #N ")" ::: "memory")
#define WAITCNT_LGKM0 asm volatile("s_waitcnt lgkmcnt(0)" ::: "memory")

// ---------------- fp32 -> bf16 convert: weights only (4 segments) ----------------
struct CvtArgs {
  const float* in[4];
  bf16* out[4];
  int n4;
  float sc[4];
};

__global__ __launch_bounds__(256) void cvt_w4(CvtArgs a) {
  const float* in = a.in[blockIdx.z];
  bf16* out = a.out[blockIdx.z];
  const float s = a.sc[blockIdx.z];
  int i = blockIdx.x * 256 + threadIdx.x;
  const int stride = gridDim.x * 256;
  for (; i < a.n4; i += stride) {
    float4 v = reinterpret_cast<const float4*>(in)[i];
    bf16x4 o;
    o[0] = (bf16)(v.x * s); o[1] = (bf16)(v.y * s);
    o[2] = (bf16)(v.z * s); o[3] = (bf16)(v.w * s);
    reinterpret_cast<bf16x4*>(out)[i] = o;
  }
}

// ---------------- gemm_qkv: f32 A staged via global_load_lds, cvt at fragment read ------
// R20/R22-proven variant (108.8-109.4us total) — session best. R23's transpose-fusion
// regressed (VGPR 80->96, occupancy 25->15%) and was reverted.
// 768 blocks = 8 XCD-chunks x 96; orig = x + 8y + 256z.
__global__ __launch_bounds__(256) void gemm_qkv(
    const float* __restrict__ qa, const bf16* __restrict__ wq, bf16* __restrict__ qo,
    const float* __restrict__ ka, const bf16* __restrict__ wk, bf16* __restrict__ ko,
    const float* __restrict__ va, const bf16* __restrict__ wv, bf16* __restrict__ vo) {
  const int n = blockIdx.x;
  const int orig = (n & 7) * 96 + (n >> 3);  // chunked XCD remap (bijective 8x96)
  const int x = orig & 7, y = (orig >> 3) & 31, z = orig >> 8;
  const float* A; const bf16* Bw; bf16* C;
  if (z == 0)      { A = qa; Bw = wq; C = qo; }
  else if (z == 1) { A = ka; Bw = wk; C = ko; }
  else             { A = va; Bw = wv; C = vo; }

  const int t = threadIdx.x;
  const int l = t & 63, w = t >> 6;
  const int wr = w >> 1, wc = w & 1;
  const int lc = l & 15, lg = l >> 4;
  const int row0 = y * 128, col0 = x * 128;

  __shared__ float Asf[128 * 32];  // 16KB: f32 A-tile, row = 128B = 8 chunks
  __shared__ bf16  Bs[128 * 32];   // 8KB

  f32x4 acc[4][4] = {};

  for (int k0 = 0; k0 < Dn; k0 += 32) {
    // stage A (f32): 1024 chunks, 4/thread; slot j holds source chunk j^(r&7)
#pragma unroll
    for (int i = 0; i < 4; ++i) {
      const int c = i * 256 + t;
      const int r = c >> 3;
      const int sj = (c & 7) ^ (r & 7);
      gload_lds16(A + (size_t)(row0 + r) * Dn + k0 + sj * 4, (char*)Asf + c * 16);
    }
    // stage B (bf16): 512 chunks, 2/thread (R13-proven layout)
#pragma unroll
    for (int i = 0; i < 2; ++i) {
      const int c = i * 256 + t;
      const int r = c >> 2;
      const int scc = (c & 3) ^ (r & 3);
      gload_lds16(Bw + (size_t)(col0 + r) * Dn + k0 + scc * 8, Bs + c * 8);
    }
    __syncthreads();

    bf16x8 af[4], bfr[4];
#pragma unroll
    for (int m = 0; m < 4; ++m) {
      const int r = wr * 64 + m * 16 + lc;
      const int sA = (2 * lg) ^ (r & 7);
      const int sB2 = (2 * lg + 1) ^ (r & 7);
      const float4 fa = *reinterpret_cast<const float4*>(Asf + r * 32 + sA * 4);
      const float4 fb = *reinterpret_cast<const float4*>(Asf + r * 32 + sB2 * 4);
      u32x4 u;
      u[0] = cvt_pk_bf16(fa.x, fa.y);
      u[1] = cvt_pk_bf16(fa.z, fa.w);
      u[2] = cvt_pk_bf16(fb.x, fb.y);
      u[3] = cvt_pk_bf16(fb.z, fb.w);
      af[m] = __builtin_bit_cast(bf16x8, u);
    }
#pragma unroll
    for (int nn = 0; nn < 4; ++nn) {
      const int r = wc * 64 + nn * 16 + lc;
      bfr[nn] = *reinterpret_cast<const bf16x8*>(Bs + r * 32 + ((lg ^ (r & 3)) * 8));
    }
#pragma unroll
    for (int m = 0; m < 4; ++m)
#pragma unroll
      for (int nn = 0; nn < 4; ++nn)
        acc[m][nn] = mfma_bf16_16x16x32(af[m], bfr[nn], acc[m][nn]);
    __syncthreads();
  }

#pragma unroll
  for (int m = 0; m < 4; ++m) {
    const int rbase = row0 + wr * 64 + m * 16 + lg * 4;
#pragma unroll
    for (int nn = 0; nn < 4; ++nn) {
      const int col = col0 + wc * 64 + nn * 16 + lc;
#pragma unroll
      for (int j = 0; j < 4; ++j)
        C[(size_t)(rbase + j) * Dn + col] = (bf16)acc[m][nn][j];
    }
  }
}

// ---------------- gemm_out: 128x128 tile, in-block K-split (8 waves; R19-proven) --------
__global__ __launch_bounds__(512) void gemm_out_f32(const bf16* __restrict__ A,
                                                    const bf16* __restrict__ Bw,
                                                    float* __restrict__ C) {
  const int n = blockIdx.x;
  const int orig = (n & 7) * 32 + (n >> 3);  // chunked XCD remap (bijective 8x32)
  const int x = orig & 7, y = orig >> 3;
  const int row0 = y * 128, col0 = x * 128;

  const int t = threadIdx.x;
  const int half = t >> 8;       // 0: K[0,512), 1: K[512,1024)
  const int tl = t & 255;
  const int l = tl & 63, wl = tl >> 6;
  const int wr = wl >> 1, wc = wl & 1;
  const int lc = l & 15, lg = l >> 4;

  __shared__ char smem[65536];   // staging: 2 x 16KB; merge: full 64KB f32 tile
  bf16* As = (bf16*)(smem + half * 16384);
  bf16* Bs = (bf16*)(smem + half * 16384 + 8192);

  f32x4 acc[4][4] = {};
  const int kbase = half * 512;

  for (int k0i = 0; k0i < 512; k0i += 32) {
    const int k0 = kbase + k0i;
#pragma unroll
    for (int i = 0; i < 2; ++i) {
      const int c = i * 256 + tl;
      const int r = c >> 2;
      const int scc = (c & 3) ^ (r & 3);
      gload_lds16(A + (size_t)(row0 + r) * Dn + k0 + scc * 8, As + c * 8);
      gload_lds16(Bw + (size_t)(col0 + r) * Dn + k0 + scc * 8, Bs + c * 8);
    }
    __syncthreads();

    bf16x8 af[4], bfr[4];
#pragma unroll
    for (int m = 0; m < 4; ++m) {
      const int r = wr * 64 + m * 16 + lc;
      af[m] = *reinterpret_cast<const bf16x8*>(As + r * 32 + ((lg ^ (r & 3)) * 8));
    }
#pragma unroll
    for (int nn = 0; nn < 4; ++nn) {
      const int r = wc * 64 + nn * 16 + lc;
      bfr[nn] = *reinterpret_cast<const bf16x8*>(Bs + r * 32 + ((lg ^ (r & 3)) * 8));
    }
#pragma unroll
    for (int m = 0; m < 4; ++m)
#pragma unroll
      for (int nn = 0; nn < 4; ++nn)
        acc[m][nn] = mfma_bf16_16x16x32(af[m], bfr[nn], acc[m][nn]);
    __syncthreads();  // last iteration: staging reads retired before publish
  }

  float* Op = (float*)smem;  // [128][128] f32
  if (half == 1) {
#pragma unroll
    for (int m = 0; m < 4; ++m) {
      const int rl = wr * 64 + m * 16 + lg * 4;
#pragma unroll
      for (int nn = 0; nn < 4; ++nn) {
        const int cl = wc * 64 + nn * 16 + lc;
#pragma unroll
        for (int j = 0; j < 4; ++j)
          Op[(rl + j) * 128 + cl] = acc[m][nn][j];
      }
    }
  }
  __syncthreads();

  if (half == 0) {
#pragma unroll
    for (int m = 0; m < 4; ++m) {
      const int rl = wr * 64 + m * 16 + lg * 4;
#pragma unroll
      for (int nn = 0; nn < 4; ++nn) {
        const int cl = wc * 64 + nn * 16 + lc;
#pragma unroll
        for (int j = 0; j < 4; ++j)
          C[(size_t)(row0 + rl + j) * Dn + col0 + cl] =
              acc[m][nn][j] + Op[(rl + j) * 128 + cl];
      }
    }
  }
}

// ---------------- per-batch transpose (S x D) -> (D x S) for V ----------------
__global__ __launch_bounds__(256) void transpose_bsd(const bf16* __restrict__ in,
                                                     bf16* __restrict__ out) {
  __shared__ bf16 tile[64][66];
  const int s0 = blockIdx.x * 64, d0 = blockIdx.y * 64, b = blockIdx.z;
  const int t = threadIdx.x;
#pragma unroll
  for (int i = 0; i < 2; ++i) {
    const int c = i * 256 + t;
    const int r = c >> 3, cc = (c & 7) * 8;
    const bf16x8 v = *reinterpret_cast<const bf16x8*>(
        in + ((size_t)b * Sn + s0 + r) * Dn + d0 + cc);
#pragma unroll
    for (int j = 0; j < 8; ++j) tile[r][cc + j] = v[j];
  }
  __syncthreads();
#pragma unroll
  for (int i = 0; i < 2; ++i) {
    const int c = i * 256 + t;
    const int r = c >> 3, cc = (c & 7) * 8;
    bf16x8 v;
#pragma unroll
    for (int j = 0; j < 8; ++j) v[j] = tile[cc + j][r];
    *reinterpret_cast<bf16x8*>(out + ((size_t)b * Dn + d0 + r) * Sn + s0 + cc) = v;
  }
}

// ---------------- causal flash attention (v11: KV-split + paired qt, uniform) ------------
// (R13-proven kernel, unchanged: ~50us, occupancy 18.6%)
__global__ __launch_bounds__(512) void flash_attn(const bf16* __restrict__ qp,
                                                  const bf16* __restrict__ kp,
                                                  const bf16* __restrict__ vt,
                                                  bf16* __restrict__ ctx) {
  const int n = blockIdx.x;
  const int g = (n & 7) + 8 * (n >> 6);
  const int pid = (n >> 3) & 7;
  const int h = g & 15;
  const int b = g >> 4;
  const int t = threadIdx.x, w = t >> 6, l = t & 63;
  const int lq = l & 31, hi = l >> 5;
  const int half = w >> 2;             // 0: chunk0 waves, 1: chunk1 waves

  __shared__ char smem[81920];
  char* my = smem + half * 40960;      // my half's staging region

  const int tl = t & 255;
  const int rl = tl >> 3;
  const int scc = (tl & 7) ^ (rl & 7);
  const bf16* kbase = kp + ((size_t)b * Sn + rl) * Dn + h * HDn + scc * 8;
  const bf16* vbase = vt + ((size_t)b * Dn + h * HDn + rl) * Sn + scc * 8;

  for (int ph = 0; ph < 2; ++ph) {
    const int qt = ph ? pid : 15 - pid;
    const int qrow0 = qt * 128 + (w & 3) * 32;
    const int cnt = qt + 1;            // tiles per chunk (same for both halves)
    const int tbase = half * cnt;

    auto STAGE = [&](int i) {
      const int kv0 = (tbase + i) * 64;
      char* Kd = my + (i & 1) * 8192 + tl * 16;
      char* Vd = my + 16384 + (i % 3) * 8192 + tl * 16;
      const bf16* ks = kbase + (size_t)kv0 * Dn;
      const bf16* vs = vbase + kv0;
#pragma unroll
      for (int ii = 0; ii < 2; ++ii) {
        gload_lds16(ks + (size_t)ii * 32 * Dn, Kd + ii * 4096);
        gload_lds16(vs + (size_t)ii * 32 * Sn, Vd + ii * 4096);
      }
    };

    bf16x8 qf[4];
#pragma unroll
    for (int kk = 0; kk < 4; ++kk)
      qf[kk] = *reinterpret_cast<const bf16x8*>(
          qp + ((size_t)b * Sn + qrow0 + lq) * Dn + h * HDn + kk * 16 + hi * 8);

    f32x16 oacc0 = {}, oacc1 = {};
    float mrow = -1e30f, lsum = 0.0f;

    auto QK = [&](int i, f32x16& s0_, f32x16& s1_) {
      const char* Kc = my + (i & 1) * 8192;
      __builtin_amdgcn_s_setprio(1);
#pragma unroll
      for (int kk = 0; kk < 4; ++kk) {
        const int ch = kk * 2 + hi;
        const int r0 = lq, r1 = 32 + lq;
        const bf16x8 k0 = *reinterpret_cast<const bf16x8*>(Kc + r0 * 128 + ((ch ^ (r0 & 7)) << 4));
        const bf16x8 k1 = *reinterpret_cast<const bf16x8*>(Kc + r1 * 128 + ((ch ^ (r1 & 7)) << 4));
        s0_ = mfma_bf16_32x32x16(k0, qf[kk], s0_);
        s1_ = mfma_bf16_32x32x16(k1, qf[kk], s1_);
      }
      __builtin_amdgcn_s_setprio(0);
    };

    auto SMPV = [&](int i, f32x16& s0, f32x16& s1) {
      const int kv0 = (tbase + i) * 64;
      const char* Vc = my + 16384 + (i % 3) * 8192;

      if (kv0 + 63 > qrow0) {
        const int qg = qrow0 + lq;
#pragma unroll
        for (int r = 0; r < 16; ++r) {
          const int kvl = (r & 3) + 8 * (r >> 2) + 4 * hi;
          if (kv0 + kvl > qg)      s0[r] = -1e30f;
          if (kv0 + 32 + kvl > qg) s1[r] = -1e30f;
        }
      }

      float mx[8];
#pragma unroll
      for (int i2 = 0; i2 < 8; ++i2)
        mx[i2] = fmaxf(fmaxf(s0[i2], s0[i2 + 8]), fmaxf(s1[i2], s1[i2 + 8]));
#pragma unroll
      for (int i2 = 0; i2 < 4; ++i2) mx[i2] = fmaxf(mx[i2], mx[i2 + 4]);
      const float tmax_own = fmaxf(fmaxf(mx[0], mx[1]), fmaxf(mx[2], mx[3]));
      const float tmax = cross_half_max(tmax_own);

      float alpha = 1.0f;
      if (!__all(tmax <= mrow + 8.0f)) {  // defer-max (T13)
        const float mn = fmaxf(mrow, tmax);
        alpha = fast_exp2(mrow - mn);
        mrow = mn;
#pragma unroll
        for (int r = 0; r < 16; ++r) { oacc0[r] *= alpha; oacc1[r] *= alpha; }
      }
#pragma unroll
      for (int r = 0; r < 16; ++r) {
        s0[r] = fast_exp2(s0[r] - mrow);
        s1[r] = fast_exp2(s1[r] - mrow);
      }
      float sm[8];
#pragma unroll
      for (int i2 = 0; i2 < 8; ++i2)
        sm[i2] = (s0[i2] + s0[i2 + 8]) + (s1[i2] + s1[i2 + 8]);
#pragma unroll
      for (int i2 = 0; i2 < 4; ++i2) sm[i2] += sm[i2 + 4];
      float rsum = (sm[0] + sm[1]) + (sm[2] + sm[3]);
      rsum = cross_half_add(rsum);
      lsum = lsum * alpha + rsum;

      u32x4 pw[4];
#pragma unroll
      for (int c2 = 0; c2 < 4; ++c2) {
        const f32x16& S = (c2 < 2) ? s0 : s1;
        const int base = (c2 & 1) * 8;
        const unsigned u0 = cvt_pk_bf16(S[base + 0], S[base + 1]);
        const unsigned u1 = cvt_pk_bf16(S[base + 2], S[base + 3]);
        const unsigned u2 = cvt_pk_bf16(S[base + 4], S[base + 5]);
        const unsigned u3 = cvt_pk_bf16(S[base + 6], S[base + 7]);
        const unsigned r1 = shfl32u(hi ? u0 : u2);
        const unsigned r2 = shfl32u(hi ? u1 : u3);
        pw[c2][0] = hi ? r1 : u0;
        pw[c2][1] = hi ? r2 : u1;
        pw[c2][2] = hi ? u2 : r1;
        pw[c2][3] = hi ? u3 : r2;
      }

      __builtin_amdgcn_s_setprio(1);
#pragma unroll
      for (int kk = 0; kk < 4; ++kk) {
        const bf16x8 pf = __builtin_bit_cast(bf16x8, pw[kk]);
        const int ch = kk * 2 + hi;
        const int r0 = lq, r1 = 32 + lq;
        const bf16x8 v0 = *reinterpret_cast<const bf16x8*>(Vc + r0 * 128 + ((ch ^ (r0 & 7)) << 4));
        const bf16x8 v1 = *reinterpret_cast<const bf16x8*>(Vc + r1 * 128 + ((ch ^ (r1 & 7)) << 4));
        oacc0 = mfma_bf16_32x32x16(v0, pf, oacc0);
        oacc1 = mfma_bf16_32x32x16(v1, pf, oacc1);
      }
      __builtin_amdgcn_s_setprio(0);
    };

    // phase-top barrier: prior-phase epilogue LDS reads retired before STAGE writes
    __builtin_amdgcn_s_barrier();
    __builtin_amdgcn_sched_barrier(0);

    STAGE(0);
    if (cnt > 1) { STAGE(1); WAITCNT_VM(4); } else { WAITCNT_VM(0); }
    __builtin_amdgcn_sched_barrier(0);
    __builtin_amdgcn_s_barrier();
    __builtin_amdgcn_sched_barrier(0);

    f32x16 sp0 = {}, sp1 = {};
    if (tbase * 64 <= qrow0 + 31) QK(0, sp0, sp1);

    for (int i = 0; i < cnt; ++i) {
      WAITCNT_VM(0);
      __builtin_amdgcn_sched_barrier(0);
      __builtin_amdgcn_s_barrier();
      __builtin_amdgcn_sched_barrier(0);

      if (i + 2 < cnt) STAGE(i + 2);
      f32x16 sn0 = {}, sn1 = {};
      if (i + 1 < cnt && (tbase + i + 1) * 64 <= qrow0 + 31) QK(i + 1, sn0, sn1);
      if ((tbase + i) * 64 <= qrow0 + 31) SMPV(i, sp0, sp1);
      sp0 = sn0; sp1 = sn1;
      WAITCNT_LGKM0;
    }

    // race-fix barrier (R10 lesson)
    __builtin_amdgcn_s_barrier();
    __builtin_amdgcn_sched_barrier(0);

    float* Op = (float*)smem;
    float* Ml = (float*)(smem + 33280);
    const int lrow = (w & 3) * 32 + lq;

    if (half == 1) {
#pragma unroll
      for (int r = 0; r < 16; ++r) {
        const int d = (r & 3) + 8 * (r >> 2) + 4 * hi;
        Op[lrow * 65 + d]      = oacc0[r];
        Op[lrow * 65 + 32 + d] = oacc1[r];
      }
      if (hi == 0) { Ml[lrow] = mrow; Ml[128 + lrow] = lsum; }
    }
    WAITCNT_LGKM0;
    __builtin_amdgcn_s_barrier();
    __builtin_amdgcn_sched_barrier(0);

    if (half == 0) {
      const float m1 = Ml[lrow], l1 = Ml[128 + lrow];
      const float mm = fmaxf(mrow, m1);
      const float a0 = fast_exp2(mrow - mm);
      const float a1 = fast_exp2(m1 - mm);
      const float inv = 1.0f / (lsum * a0 + l1 * a1);

      bf16* ep = (bf16*)(smem + 40960 + w * 4608);
#pragma unroll
      for (int dt = 0; dt < 2; ++dt) {
        const f32x16& O = dt ? oacc1 : oacc0;
#pragma unroll
        for (int g2 = 0; g2 < 4; ++g2) {
          bf16x4 o4;
#pragma unroll
          for (int jj = 0; jj < 4; ++jj) {
            const int d = dt * 32 + 8 * g2 + 4 * hi + jj;
            const float o1 = Op[lrow * 65 + d];
            o4[jj] = (bf16)((O[g2 * 4 + jj] * a0 + o1 * a1) * inv);
          }
          const int d0 = dt * 32 + g2 * 8 + hi * 4;
          *reinterpret_cast<bf16x4*>(&ep[lq * 72 + d0]) = o4;
        }
      }
      WAITCNT_LGKM0;
      __builtin_amdgcn_sched_barrier(0);
#pragma unroll
      for (int i = 0; i < 4; ++i) {
        const int q = i * 8 + (l >> 3);
        const int d0 = (l & 7) * 8;
        const bf16x8 vv = *reinterpret_cast<const bf16x8*>(&ep[q * 72 + d0]);
        *reinterpret_cast<bf16x8*>(
            &ctx[((size_t)b * Sn + qrow0 + q) * Dn + h * HDn + d0]) = vv;
      }
    }
  }
}

// ---------------- launch ----------------
extern "C" void kernel_launch(void* const* d_in, const int* in_sizes, int n_in,
                              void* d_out, int out_size, void* d_ws, size_t ws_size,
                              hipStream_t stream) {
  const float* q  = (const float*)d_in[0];
  const float* k  = (const float*)d_in[1];
  const float* v  = (const float*)d_in[2];
  // d_in[3] = causal mask (structure known; unused)
  const float* Wq = (const float*)d_in[4];
  const float* Wk = (const float*)d_in[5];
  const float* Wv = (const float*)d_in[6];
  const float* Wo = (const float*)d_in[7];

  constexpr size_t BSD = (size_t)Bn * Sn * Dn;
  constexpr size_t DD  = (size_t)Dn * Dn;

  char* p = (char*)d_ws;
  bf16* ctxb = (bf16*)p; p += BSD * 2;
  bf16* vtb  = (bf16*)p; p += BSD * 2;
  p += BSD * 2;
  bf16* qpb = (bf16*)p; p += BSD * 2;
  bf16* kpb = (bf16*)p; p += BSD * 2;
  bf16* vpb = (bf16*)p; p += BSD * 2;
  bf16* wqb = (bf16*)p; p += DD * 2;
  bf16* wkb = (bf16*)p; p += DD * 2;
  bf16* wvb = (bf16*)p; p += DD * 2;
  bf16* wob = (bf16*)p; p += DD * 2;

  // fold softmax scale (1/sqrt(64)=1/8) and log2(e) into Wq for exp2-domain softmax
  const float wq_scale = 0.125f * 1.4426950408889634f;

  CvtArgs ca;
  ca.in[0] = Wq; ca.out[0] = wqb; ca.sc[0] = wq_scale;
  ca.in[1] = Wk; ca.out[1] = wkb; ca.sc[1] = 1.0f;
  ca.in[2] = Wv; ca.out[2] = wvb; ca.sc[2] = 1.0f;
  ca.in[3] = Wo; ca.out[3] = wob; ca.sc[3] = 1.0f;
  ca.n4 = (int)(DD / 4);
  cvt_w4<<<dim3(256, 1, 4), 256, 0, stream>>>(ca);

  gemm_qkv<<<dim3(768), 256, 0, stream>>>(
      q, wqb, qpb, k, wkb, kpb, v, wvb, vpb);

  transpose_bsd<<<dim3(Sn / 64, Dn / 64, Bn), 256, 0, stream>>>(vpb, vtb);

  flash_attn<<<dim3(256), 512, 0, stream>>>(qpb, kpb, vtb, ctxb);

  gemm_out_f32<<<dim3(256), 512, 0, stream>>>(ctxb, wob, (float*)d_out);

  (void)in_sizes; (void)n_in; (void)out_size; (void)ws_size;
}